// Round 14
// baseline (2652.366 us; speedup 1.0000x reference)
//
#include <hip/hip_runtime.h>
#include <math.h>

#define NFFT 1024
#define BLK  512   // 8 waves, ONE batch per block; grid = 128

// ---- DPP cross-lane (VALU pipe), HW-validated R6/R10 ----
// packed ext_vector_type math BANNED (R8/R9). permlane swap builtins verified R10.
template <int CTRL>
__device__ __forceinline__ float dppf(float v) {
    return __int_as_float(__builtin_amdgcn_update_dpp(
        0, __float_as_int(v), CTRL, 0xF, 0xF, true));
}
__device__ __forceinline__ float qx1(float v) { return dppf<0xB1>(v); }   // l^1
__device__ __forceinline__ float qx2(float v) { return dppf<0x4E>(v); }   // l^2
__device__ __forceinline__ float xr4(float v) { return dppf<0x1B>(dppf<0x141>(v)); } // l^4
__device__ __forceinline__ float xr8(float v) { return dppf<0x128>(v); }  // l^8

__device__ __forceinline__ void pswap16(float v, float& lo, float& hi) {
    auto r = __builtin_amdgcn_permlane16_swap(__float_as_int(v), __float_as_int(v),
                                              false, false);
    lo = __int_as_float(r[0]);
    hi = __int_as_float(r[1]);
}
__device__ __forceinline__ void pswap32(float v, float& lo, float& hi) {
    auto r = __builtin_amdgcn_permlane32_swap(__float_as_int(v), __float_as_int(v),
                                              false, false);
    lo = __int_as_float(r[0]);
    hi = __int_as_float(r[1]);
}

__global__ __launch_bounds__(BLK, 2)
void siva_kernel(const float* __restrict__ x,
                 const float* __restrict__ nu_p,
                 const float* __restrict__ dto_p,
                 const float* __restrict__ cr_p,
                 const int* __restrict__ nt_p,
                 const int* __restrict__ ns_p,
                 float* __restrict__ out) {
    // one exchange per substep, parity double-buffered (WAR-safe with 1 barrier)
    __shared__ float4 buf[2][BLK];

    const int tt = threadIdx.x;    // 0..511
    const int b  = blockIdx.x;
    const int l  = tt & 63;
    const int w  = tt >> 6;        // wave 0..7
    const int a0 = 2 * w;          // slot indices a = 2w+p  (digit a of n = 16b+a)
    const int a1 = 2 * w + 1;
    const int kb = (int)(__brev((unsigned)l) >> 26);   // rev6(l): spectral lane pos

    const int nT   = nt_p[0];
    const int nsub = ns_p[0];

    const float nu  = (1.0f / (1.0f + expf(-nu_p[0])))  * (0.5f - 0.01f)  + 0.01f;
    const float dto = (1.0f / (1.0f + expf(-dto_p[0]))) * (0.1f - 0.001f) + 0.001f;
    const float cR  = (1.0f / (1.0f + expf(-cr_p[0])))  * (2.0f - 0.5f)   + 0.5f;
    const float dt   = dto / (float)nsub;
    const float dtcR = dt * cR;

    // Lane-64 radix-2 tables (Round-2/R13 verified machinery).
    float2 wf[6]; float sg[6]; float2 wi[6];
    #pragma unroll
    for (int s = 0; s < 6; ++s) {
        const int h = 32 >> s;
        const int lm = l & (h - 1);
        const bool hif = (l & h) != 0;
        const float a = (float)(lm * (32 / h)) * (1.0f / 32.0f);   // pi units
        wf[s] = hif ? make_float2(cospif(a), -sinpif(a)) : make_float2(1.0f, 0.0f);
        sg[s] = hif ? -1.0f : 1.0f;
        const int h2 = 1 << s;
        const int lm2 = l & (h2 - 1);
        const float a2 = (float)lm2 / (float)h2;
        float2 wb = make_float2(cospif(a2), sinpif(a2));
        if ((l & h2) != 0) { wb.x = -wb.x; wb.y = -wb.y; }
        wi[s] = wb;
    }
    // select-free inverse butterflies for DPP stages s=0..3 (h=1,2,4,8)
    // z' = cai*own + cbi*partner (R13-verified construction)
    float2 cai[4], cbi[4];
    #pragma unroll
    for (int s = 0; s < 4; ++s) {
        const bool hif = (l & (1 << s)) != 0;
        cai[s] = hif ? wi[s] : make_float2(1.0f, 0.0f);
        cbi[s] = hif ? make_float2(1.0f, 0.0f) : wi[s];
    }

    // Substep spectral multiplier S_plain(k) at the 16 positions k = kb + 64*ka.
    float mS[16];
    #pragma unroll
    for (int ka = 0; ka < 16; ++ka) {
        const int k = kb + 64 * ka;
        const float kk = (k <= 512) ? (float)k : (float)(k - 1024);
        const float kab = fabsf(kk);
        const float q = 1.0f - dtcR * (kab - nu * kab * kab);
        const float kkS = (k == 0 || k == 512) ? 0.0f : kk;
        mS[ka] = (1.0f - dt * kkS) / q;
    }

    // Build fused-exchange rows for a real multiplier m(k):
    // row_p[a'] = W1024^{(a'-ap)kb} * (1/1024) * sum_ka W16^{(a'-ap)ka} m[ka]
    // (W_N = e^{-2pi i/N}; all indices compile-time -> registers)
    auto buildRows = [&](const float* m, float2* r0, float2* r1) {
        #pragma unroll
        for (int aq = 0; aq < 16; ++aq) {
            {
                const float d = (float)(aq - a0);
                float sx = 0.0f, sy = 0.0f;
                #pragma unroll
                for (int ka = 0; ka < 16; ++ka) {
                    const float ang = d * (float)ka * 0.125f;   // pi units
                    sx = fmaf(m[ka], cospif(ang), sx);
                    sy = fmaf(m[ka], -sinpif(ang), sy);
                }
                const float angb = d * (float)kb * (1.0f / 512.0f);
                const float cb = cospif(angb), sb = -sinpif(angb);
                r0[aq] = make_float2((cb * sx - sb * sy) * (1.0f / 1024.0f),
                                     (cb * sy + sb * sx) * (1.0f / 1024.0f));
            }
            {
                const float d = (float)(aq - a1);
                float sx = 0.0f, sy = 0.0f;
                #pragma unroll
                for (int ka = 0; ka < 16; ++ka) {
                    const float ang = d * (float)ka * 0.125f;
                    sx = fmaf(m[ka], cospif(ang), sx);
                    sy = fmaf(m[ka], -sinpif(ang), sy);
                }
                const float angb = d * (float)kb * (1.0f / 512.0f);
                const float cb = cospif(angb), sb = -sinpif(angb);
                r1[aq] = make_float2((cb * sx - sb * sy) * (1.0f / 1024.0f),
                                     (cb * sy + sb * sx) * (1.0f / 1024.0f));
            }
        }
    };

    // persistent substep rows
    float2 rS0[16], rS1[16];
    buildRows(mS, rS0, rS1);

    // fwd DIF step: z = wf[s] * (partner + sg[s]*z)
    auto fwd_s = [&](float2& zz, float bx, float by, int s) {
        const float tx = fmaf(sg[s], zz.x, bx);
        const float ty = fmaf(sg[s], zz.y, by);
        zz.x = tx * wf[s].x - ty * wf[s].y;
        zz.y = tx * wf[s].y + ty * wf[s].x;
    };
    // select-free inverse DPP step: z' = cai*own + cbi*partner
    auto inv_sf = [&](float2& zz, float px, float py, int s) {
        const float nx = fmaf(cai[s].x, zz.x, fmaf(-cai[s].y, zz.y,
                         fmaf(cbi[s].x, px, -cbi[s].y * py)));
        const float ny = fmaf(cai[s].x, zz.y, fmaf(cai[s].y, zz.x,
                         fmaf(cbi[s].x, py, cbi[s].y * px)));
        zz = make_float2(nx, ny);
    };

    // full 6-stage forward lane FFT-64 (natural l -> spectral rev6(l))
    auto lane_fwd6 = [&](float2 z[2]) {
        #pragma unroll
        for (int r = 0; r < 2; ++r) {
            float lox, hix, loy, hiy;
            pswap32(z[r].x, lox, hix); pswap32(z[r].y, loy, hiy);
            const float tx = fmaf(sg[0], hix, lox);
            const float ty = fmaf(sg[0], hiy, loy);
            z[r].x = tx * wf[0].x - ty * wf[0].y;
            z[r].y = tx * wf[0].y + ty * wf[0].x;
        }
        #pragma unroll
        for (int r = 0; r < 2; ++r) {
            float lox, hix, loy, hiy;
            pswap16(z[r].x, lox, hix); pswap16(z[r].y, loy, hiy);
            const float tx = fmaf(sg[1], hix, lox);
            const float ty = fmaf(sg[1], hiy, loy);
            z[r].x = tx * wf[1].x - ty * wf[1].y;
            z[r].y = tx * wf[1].y + ty * wf[1].x;
        }
        #pragma unroll
        for (int r = 0; r < 2; ++r) fwd_s(z[r], xr8(z[r].x), xr8(z[r].y), 2);
        #pragma unroll
        for (int r = 0; r < 2; ++r) fwd_s(z[r], xr4(z[r].x), xr4(z[r].y), 3);
        #pragma unroll
        for (int r = 0; r < 2; ++r) fwd_s(z[r], qx2(z[r].x), qx2(z[r].y), 4);
        #pragma unroll
        for (int r = 0; r < 2; ++r) fwd_s(z[r], qx1(z[r].x), qx1(z[r].y), 5);
    };
    // full 6-stage inverse lane FFT-64 (spectral rev6(l) -> natural l), no 1/64
    auto lane_inv6 = [&](float2 z[2]) {
        #pragma unroll
        for (int r = 0; r < 2; ++r) inv_sf(z[r], qx1(z[r].x), qx1(z[r].y), 0);
        #pragma unroll
        for (int r = 0; r < 2; ++r) inv_sf(z[r], qx2(z[r].x), qx2(z[r].y), 1);
        #pragma unroll
        for (int r = 0; r < 2; ++r) inv_sf(z[r], xr4(z[r].x), xr4(z[r].y), 2);
        #pragma unroll
        for (int r = 0; r < 2; ++r) inv_sf(z[r], xr8(z[r].x), xr8(z[r].y), 3);
        #pragma unroll
        for (int r = 0; r < 2; ++r) {
            float lox, hix, loy, hiy;
            pswap16(z[r].x, lox, hix); pswap16(z[r].y, loy, hiy);
            z[r].x = fmaf(wi[4].x, hix, fmaf(-wi[4].y, hiy, lox));
            z[r].y = fmaf(wi[4].x, hiy, fmaf( wi[4].y, hix, loy));
        }
        #pragma unroll
        for (int r = 0; r < 2; ++r) {
            float lox, hix, loy, hiy;
            pswap32(z[r].x, lox, hix); pswap32(z[r].y, loy, hiy);
            z[r].x = fmaf(wi[5].x, hix, fmaf(-wi[5].y, hiy, lox));
            z[r].y = fmaf(wi[5].x, hiy, fmaf( wi[5].y, hix, loy));
        }
    };

    int par = 0;
    // one fused exchange: write both slots, barrier, 16-term mix with given rows
    auto exchange = [&](float2 z[2], const float2* r0, const float2* r1) {
        buf[par][tt] = make_float4(z[0].x, z[0].y, z[1].x, z[1].y);
        __syncthreads();
        float ax0 = 0.0f, ay0 = 0.0f, ax1 = 0.0f, ay1 = 0.0f;
        #pragma unroll
        for (int wq = 0; wq < 8; ++wq) {
            const float4 v = buf[par][wq * 64 + l];
            const float2 cA0 = r0[2 * wq], cB0 = r0[2 * wq + 1];
            const float2 cA1 = r1[2 * wq], cB1 = r1[2 * wq + 1];
            ax0 = fmaf(cA0.x, v.x, ax0);  ax0 = fmaf(-cA0.y, v.y, ax0);
            ay0 = fmaf(cA0.x, v.y, ay0);  ay0 = fmaf( cA0.y, v.x, ay0);
            ax0 = fmaf(cB0.x, v.z, ax0);  ax0 = fmaf(-cB0.y, v.w, ax0);
            ay0 = fmaf(cB0.x, v.w, ay0);  ay0 = fmaf( cB0.y, v.z, ay0);
            ax1 = fmaf(cA1.x, v.x, ax1);  ax1 = fmaf(-cA1.y, v.y, ax1);
            ay1 = fmaf(cA1.x, v.y, ay1);  ay1 = fmaf( cA1.y, v.x, ay1);
            ax1 = fmaf(cB1.x, v.z, ax1);  ax1 = fmaf(-cB1.y, v.w, ax1);
            ay1 = fmaf(cB1.x, v.w, ay1);  ay1 = fmaf( cB1.y, v.z, ay1);
        }
        z[0] = make_float2(ax0, ay0);
        z[1] = make_float2(ax1, ay1);
        par ^= 1;
    };

    // ---- init: d_to_u.  u = Re(ifft(i*kk*D)) = -Im(ifft(kk*D)) ----
    float2 z[2];
    float u0, u1;
    z[0] = make_float2(x[b * NFFT + 16 * l + a0], 0.0f);
    z[1] = make_float2(x[b * NFFT + 16 * l + a1], 0.0f);
    {
        float mD[16];
        #pragma unroll
        for (int ka = 0; ka < 16; ++ka) {
            const int k = kb + 64 * ka;
            mD[ka] = (k <= 512) ? (float)k : (float)(k - 1024);
        }
        float2 rD0[16], rD1[16];
        buildRows(mD, rD0, rD1);
        lane_fwd6(z);
        exchange(z, rD0, rD1);
        lane_inv6(z);
        u0 = -z[0].y;
        u1 = -z[1].y;
    }

    for (int ot = 0; ot < nT; ++ot) {
        for (int ss = 0; ss < nsub; ++ss) {
            z[0] = make_float2(u0, 0.5f * u0 * u0);
            z[1] = make_float2(u1, 0.5f * u1 * u1);
            lane_fwd6(z);
            exchange(z, rS0, rS1);   // fused: DFT16 + twiddles + S + invDFT16
            lane_inv6(z);
            u0 = z[0].x;             // Re
            u1 = z[1].x;
        }
        // snapshot: u_to_d. dsol = Re(ifft(-i*(1/kk)U)) = Im(ifft((1/kk)U))
        {
            float mU[16];
            #pragma unroll
            for (int ka = 0; ka < 16; ++ka) {
                const int k = kb + 64 * ka;
                const float kk = (k <= 512) ? (float)k : (float)(k - 1024);
                mU[ka] = (k == 0) ? 0.0f : (1.0f / kk);
            }
            float2 rU0[16], rU1[16];
            buildRows(mU, rU0, rU1);
            z[0] = make_float2(u0, 0.0f);
            z[1] = make_float2(u1, 0.0f);
            lane_fwd6(z);
            exchange(z, rU0, rU1);
            lane_inv6(z);
            out[(b * NFFT + 16 * l + a0) * nT + ot] = z[0].y;  // Im
            out[(b * NFFT + 16 * l + a1) * nT + ot] = z[1].y;
        }
    }
}

extern "C" void kernel_launch(void* const* d_in, const int* in_sizes, int n_in,
                              void* d_out, int out_size, void* d_ws, size_t ws_size,
                              hipStream_t stream) {
    const float* x     = (const float*)d_in[0];
    const float* nu_p  = (const float*)d_in[1];
    const float* dto_p = (const float*)d_in[2];
    const float* cr_p  = (const float*)d_in[3];
    const int*   nt_p  = (const int*)d_in[4];
    const int*   ns_p  = (const int*)d_in[5];
    float* out = (float*)d_out;

    const int B = in_sizes[0] / NFFT;  // C == 1
    siva_kernel<<<B, BLK, 0, stream>>>(x, nu_p, dto_p, cr_p, nt_p, ns_p, out);
}

// Round 15
// 2630.994 us; speedup vs baseline: 1.0081x; 1.0081x over previous
//
#include <hip/hip_runtime.h>
#include <math.h>

#define NFFT 1024
#define BLK  512   // 8 waves, ONE batch per block; grid = 128

// ---- DPP cross-lane (VALU pipe), HW-validated R6/R10 ----
template <int CTRL>
__device__ __forceinline__ float dppf(float v) {
    return __int_as_float(__builtin_amdgcn_update_dpp(
        0, __float_as_int(v), CTRL, 0xF, 0xF, true));
}
__device__ __forceinline__ float qx1(float v) { return dppf<0xB1>(v); }   // l^1
__device__ __forceinline__ float qx2(float v) { return dppf<0x4E>(v); }   // l^2
__device__ __forceinline__ float xr4(float v) { return dppf<0x1B>(dppf<0x141>(v)); } // l^4
__device__ __forceinline__ float xr8(float v) { return dppf<0x128>(v); }  // l^8

__device__ __forceinline__ void pswap16(float v, float& lo, float& hi) {
    auto r = __builtin_amdgcn_permlane16_swap(__float_as_int(v), __float_as_int(v),
                                              false, false);
    lo = __int_as_float(r[0]);
    hi = __int_as_float(r[1]);
}
__device__ __forceinline__ void pswap32(float v, float& lo, float& hi) {
    auto r = __builtin_amdgcn_permlane32_swap(__float_as_int(v), __float_as_int(v),
                                              false, false);
    lo = __int_as_float(r[0]);
    hi = __int_as_float(r[1]);
}

// Build fused-exchange rows for real multiplier array M (16 vals at k=kb+64ka):
// Rp[aq] = W1024^{(aq-ap)kb}/1024 * sum_ka W16^{(aq-ap)ka} M[ka]
// Textual macro: all stores/loads use compile-time indices on NAMED arrays
// so SROA promotes them to registers (R14's pointer-param version spilled).
#define BUILD_ROWS(Marr, R0arr, R1arr)                                          \
    _Pragma("unroll")                                                           \
    for (int aq = 0; aq < 16; ++aq) {                                           \
        const float d0 = (float)(aq - a0);                                      \
        float sx0 = 0.0f, sy0 = 0.0f;                                           \
        _Pragma("unroll")                                                       \
        for (int ka = 0; ka < 16; ++ka) {                                       \
            const float ang = d0 * (float)ka * 0.125f;                          \
            sx0 = fmaf(Marr[ka], cospif(ang), sx0);                             \
            sy0 = fmaf(Marr[ka], -sinpif(ang), sy0);                            \
        }                                                                       \
        const float gb0 = d0 * (float)kb * (1.0f / 512.0f);                     \
        const float cb0 = cospif(gb0), sb0 = -sinpif(gb0);                      \
        R0arr[aq] = make_float2((cb0 * sx0 - sb0 * sy0) * (1.0f / 1024.0f),     \
                                (cb0 * sy0 + sb0 * sx0) * (1.0f / 1024.0f));    \
        const float d1 = (float)(aq - a1);                                      \
        float sx1 = 0.0f, sy1 = 0.0f;                                           \
        _Pragma("unroll")                                                       \
        for (int ka = 0; ka < 16; ++ka) {                                       \
            const float ang = d1 * (float)ka * 0.125f;                          \
            sx1 = fmaf(Marr[ka], cospif(ang), sx1);                             \
            sy1 = fmaf(Marr[ka], -sinpif(ang), sy1);                            \
        }                                                                       \
        const float gb1 = d1 * (float)kb * (1.0f / 512.0f);                     \
        const float cb1 = cospif(gb1), sb1 = -sinpif(gb1);                      \
        R1arr[aq] = make_float2((cb1 * sx1 - sb1 * sy1) * (1.0f / 1024.0f),     \
                                (cb1 * sy1 + sb1 * sx1) * (1.0f / 1024.0f));    \
    }

// One fused exchange on named z0,z1 with named row arrays (compile-time idx).
#define EXCHANGE(R0arr, R1arr)                                                  \
    do {                                                                        \
        buf[par][tt] = make_float4(z0.x, z0.y, z1.x, z1.y);                     \
        __syncthreads();                                                        \
        float ax0 = 0.0f, ay0 = 0.0f, ax1 = 0.0f, ay1 = 0.0f;                   \
        _Pragma("unroll")                                                       \
        for (int wq = 0; wq < 8; ++wq) {                                        \
            const float4 v = buf[par][wq * 64 + l];                             \
            const float2 cA0 = R0arr[2 * wq], cB0 = R0arr[2 * wq + 1];          \
            const float2 cA1 = R1arr[2 * wq], cB1 = R1arr[2 * wq + 1];          \
            ax0 = fmaf(cA0.x, v.x, ax0);  ax0 = fmaf(-cA0.y, v.y, ax0);         \
            ay0 = fmaf(cA0.x, v.y, ay0);  ay0 = fmaf( cA0.y, v.x, ay0);         \
            ax0 = fmaf(cB0.x, v.z, ax0);  ax0 = fmaf(-cB0.y, v.w, ax0);         \
            ay0 = fmaf(cB0.x, v.w, ay0);  ay0 = fmaf( cB0.y, v.z, ay0);         \
            ax1 = fmaf(cA1.x, v.x, ax1);  ax1 = fmaf(-cA1.y, v.y, ax1);         \
            ay1 = fmaf(cA1.x, v.y, ay1);  ay1 = fmaf( cA1.y, v.x, ay1);         \
            ax1 = fmaf(cB1.x, v.z, ax1);  ax1 = fmaf(-cB1.y, v.w, ax1);         \
            ay1 = fmaf(cB1.x, v.w, ay1);  ay1 = fmaf( cB1.y, v.z, ay1);         \
        }                                                                       \
        z0 = make_float2(ax0, ay0);                                             \
        z1 = make_float2(ax1, ay1);                                             \
        par ^= 1;                                                               \
    } while (0)

__global__ __launch_bounds__(BLK, 2)
void siva_kernel(const float* __restrict__ x,
                 const float* __restrict__ nu_p,
                 const float* __restrict__ dto_p,
                 const float* __restrict__ cr_p,
                 const int* __restrict__ nt_p,
                 const int* __restrict__ ns_p,
                 float* __restrict__ out) {
    // one exchange per substep, parity double-buffered (WAR-safe with 1 barrier)
    __shared__ float4 buf[2][BLK];

    const int tt = threadIdx.x;    // 0..511
    const int b  = blockIdx.x;
    const int l  = tt & 63;
    const int w  = tt >> 6;        // wave 0..7
    const int a0 = 2 * w;          // slot indices a = 2w+p  (digit a of n = 16b+a)
    const int a1 = 2 * w + 1;
    const int kb = (int)(__brev((unsigned)l) >> 26);   // rev6(l)

    const int nT   = nt_p[0];
    const int nsub = ns_p[0];

    const float nu  = (1.0f / (1.0f + expf(-nu_p[0])))  * (0.5f - 0.01f)  + 0.01f;
    const float dto = (1.0f / (1.0f + expf(-dto_p[0]))) * (0.1f - 0.001f) + 0.001f;
    const float cR  = (1.0f / (1.0f + expf(-cr_p[0])))  * (2.0f - 0.5f)   + 0.5f;
    const float dt   = dto / (float)nsub;
    const float dtcR = dt * cR;

    // Lane-64 radix-2 tables (Round-2/R13 verified machinery).
    float2 wf[6]; float sg[6]; float2 wi[6];
    #pragma unroll
    for (int s = 0; s < 6; ++s) {
        const int h = 32 >> s;
        const int lm = l & (h - 1);
        const bool hif = (l & h) != 0;
        const float a = (float)(lm * (32 / h)) * (1.0f / 32.0f);   // pi units
        wf[s] = hif ? make_float2(cospif(a), -sinpif(a)) : make_float2(1.0f, 0.0f);
        sg[s] = hif ? -1.0f : 1.0f;
        const int h2 = 1 << s;
        const int lm2 = l & (h2 - 1);
        const float a2 = (float)lm2 / (float)h2;
        float2 wb = make_float2(cospif(a2), sinpif(a2));
        if ((l & h2) != 0) { wb.x = -wb.x; wb.y = -wb.y; }
        wi[s] = wb;
    }
    // select-free inverse butterflies for DPP stages s=0..3 (h=1,2,4,8)
    float2 cai[4], cbi[4];
    #pragma unroll
    for (int s = 0; s < 4; ++s) {
        const bool hif = (l & (1 << s)) != 0;
        cai[s] = hif ? wi[s] : make_float2(1.0f, 0.0f);
        cbi[s] = hif ? make_float2(1.0f, 0.0f) : wi[s];
    }

    // Substep spectral multiplier at k = kb + 64*ka, then fused rows.
    float2 rS0[16], rS1[16];
    {
        float mS[16];
        #pragma unroll
        for (int ka = 0; ka < 16; ++ka) {
            const int k = kb + 64 * ka;
            const float kk = (k <= 512) ? (float)k : (float)(k - 1024);
            const float kab = fabsf(kk);
            const float q = 1.0f - dtcR * (kab - nu * kab * kab);
            const float kkS = (k == 0 || k == 512) ? 0.0f : kk;
            mS[ka] = (1.0f - dt * kkS) / q;
        }
        BUILD_ROWS(mS, rS0, rS1)
    }

    // fwd DIF step: z = wf[s] * (partner + sg[s]*z)
    auto fwd_s = [&](float2& zz, float bx, float by, int s) {
        const float tx = fmaf(sg[s], zz.x, bx);
        const float ty = fmaf(sg[s], zz.y, by);
        zz.x = tx * wf[s].x - ty * wf[s].y;
        zz.y = tx * wf[s].y + ty * wf[s].x;
    };
    // select-free inverse DPP step
    auto inv_sf = [&](float2& zz, float px, float py, int s) {
        const float nx = fmaf(cai[s].x, zz.x, fmaf(-cai[s].y, zz.y,
                         fmaf(cbi[s].x, px, -cbi[s].y * py)));
        const float ny = fmaf(cai[s].x, zz.y, fmaf(cai[s].y, zz.x,
                         fmaf(cbi[s].x, py, cbi[s].y * px)));
        zz = make_float2(nx, ny);
    };
    // one forward lane stage applied to a named float2
    auto fwd_one = [&](float2& zz, int s) {
        if (s == 0) {
            float lox, hix, loy, hiy;
            pswap32(zz.x, lox, hix); pswap32(zz.y, loy, hiy);
            const float tx = fmaf(sg[0], hix, lox);
            const float ty = fmaf(sg[0], hiy, loy);
            zz.x = tx * wf[0].x - ty * wf[0].y;
            zz.y = tx * wf[0].y + ty * wf[0].x;
        } else if (s == 1) {
            float lox, hix, loy, hiy;
            pswap16(zz.x, lox, hix); pswap16(zz.y, loy, hiy);
            const float tx = fmaf(sg[1], hix, lox);
            const float ty = fmaf(sg[1], hiy, loy);
            zz.x = tx * wf[1].x - ty * wf[1].y;
            zz.y = tx * wf[1].y + ty * wf[1].x;
        } else if (s == 2) fwd_s(zz, xr8(zz.x), xr8(zz.y), 2);
        else if (s == 3)   fwd_s(zz, xr4(zz.x), xr4(zz.y), 3);
        else if (s == 4)   fwd_s(zz, qx2(zz.x), qx2(zz.y), 4);
        else               fwd_s(zz, qx1(zz.x), qx1(zz.y), 5);
    };
    auto inv_one = [&](float2& zz, int s) {
        if (s == 0)      inv_sf(zz, qx1(zz.x), qx1(zz.y), 0);
        else if (s == 1) inv_sf(zz, qx2(zz.x), qx2(zz.y), 1);
        else if (s == 2) inv_sf(zz, xr4(zz.x), xr4(zz.y), 2);
        else if (s == 3) inv_sf(zz, xr8(zz.x), xr8(zz.y), 3);
        else if (s == 4) {
            float lox, hix, loy, hiy;
            pswap16(zz.x, lox, hix); pswap16(zz.y, loy, hiy);
            zz.x = fmaf(wi[4].x, hix, fmaf(-wi[4].y, hiy, lox));
            zz.y = fmaf(wi[4].x, hiy, fmaf( wi[4].y, hix, loy));
        } else {
            float lox, hix, loy, hiy;
            pswap32(zz.x, lox, hix); pswap32(zz.y, loy, hiy);
            zz.x = fmaf(wi[5].x, hix, fmaf(-wi[5].y, hiy, lox));
            zz.y = fmaf(wi[5].x, hiy, fmaf( wi[5].y, hix, loy));
        }
    };
    auto lane_fwd6 = [&](float2& za, float2& zb) {
        #pragma unroll
        for (int s = 0; s < 6; ++s) { fwd_one(za, s); fwd_one(zb, s); }
    };
    auto lane_inv6 = [&](float2& za, float2& zb) {
        #pragma unroll
        for (int s = 0; s < 6; ++s) { inv_one(za, s); inv_one(zb, s); }
    };

    int par = 0;
    float2 z0, z1;
    float u0, u1;

    // ---- init: d_to_u.  u = Re(ifft(i*kk*D)) = -Im(ifft(kk*D)) ----
    z0 = make_float2(x[b * NFFT + 16 * l + a0], 0.0f);
    z1 = make_float2(x[b * NFFT + 16 * l + a1], 0.0f);
    {
        float mD[16];
        #pragma unroll
        for (int ka = 0; ka < 16; ++ka) {
            const int k = kb + 64 * ka;
            mD[ka] = (k <= 512) ? (float)k : (float)(k - 1024);
        }
        float2 rD0[16], rD1[16];
        BUILD_ROWS(mD, rD0, rD1)
        lane_fwd6(z0, z1);
        EXCHANGE(rD0, rD1);
        lane_inv6(z0, z1);
        u0 = -z0.y;
        u1 = -z1.y;
    }

    for (int ot = 0; ot < nT; ++ot) {
        for (int ss = 0; ss < nsub; ++ss) {
            z0 = make_float2(u0, 0.5f * u0 * u0);
            z1 = make_float2(u1, 0.5f * u1 * u1);
            lane_fwd6(z0, z1);
            EXCHANGE(rS0, rS1);   // fused: DFT16 + twiddles + S + invDFT16
            lane_inv6(z0, z1);
            u0 = z0.x;            // Re
            u1 = z1.x;
        }
        // snapshot: u_to_d. dsol = Re(ifft(-i*(1/kk)U)) = Im(ifft((1/kk)U))
        {
            float mU[16];
            #pragma unroll
            for (int ka = 0; ka < 16; ++ka) {
                const int k = kb + 64 * ka;
                const float kk = (k <= 512) ? (float)k : (float)(k - 1024);
                mU[ka] = (k == 0) ? 0.0f : (1.0f / kk);
            }
            float2 rU0[16], rU1[16];
            BUILD_ROWS(mU, rU0, rU1)
            z0 = make_float2(u0, 0.0f);
            z1 = make_float2(u1, 0.0f);
            lane_fwd6(z0, z1);
            EXCHANGE(rU0, rU1);
            lane_inv6(z0, z1);
            out[(b * NFFT + 16 * l + a0) * nT + ot] = z0.y;  // Im
            out[(b * NFFT + 16 * l + a1) * nT + ot] = z1.y;
        }
    }
}

extern "C" void kernel_launch(void* const* d_in, const int* in_sizes, int n_in,
                              void* d_out, int out_size, void* d_ws, size_t ws_size,
                              hipStream_t stream) {
    const float* x     = (const float*)d_in[0];
    const float* nu_p  = (const float*)d_in[1];
    const float* dto_p = (const float*)d_in[2];
    const float* cr_p  = (const float*)d_in[3];
    const int*   nt_p  = (const int*)d_in[4];
    const int*   ns_p  = (const int*)d_in[5];
    float* out = (float*)d_out;

    const int B = in_sizes[0] / NFFT;  // C == 1
    siva_kernel<<<B, BLK, 0, stream>>>(x, nu_p, dto_p, cr_p, nt_p, ns_p, out);
}

// Round 16
// 713.344 us; speedup vs baseline: 3.7182x; 3.6883x over previous
//
#include <hip/hip_runtime.h>
#include <math.h>

#define NFFT 1024
#define BLK  512   // 8 waves, ONE batch per block; grid = 128

// ---- DPP cross-lane (VALU pipe), HW-validated R6/R10 ----
template <int CTRL>
__device__ __forceinline__ float dppf(float v) {
    return __int_as_float(__builtin_amdgcn_update_dpp(
        0, __float_as_int(v), CTRL, 0xF, 0xF, true));
}
__device__ __forceinline__ float qx1(float v) { return dppf<0xB1>(v); }   // l^1
__device__ __forceinline__ float qx2(float v) { return dppf<0x4E>(v); }   // l^2
__device__ __forceinline__ float xr4(float v) { return dppf<0x1B>(dppf<0x141>(v)); } // l^4
__device__ __forceinline__ float xr8(float v) { return dppf<0x128>(v); }  // l^8

__device__ __forceinline__ void pswap16(float v, float& lo, float& hi) {
    auto r = __builtin_amdgcn_permlane16_swap(__float_as_int(v), __float_as_int(v),
                                              false, false);
    lo = __int_as_float(r[0]);
    hi = __int_as_float(r[1]);
}
__device__ __forceinline__ void pswap32(float v, float& lo, float& hi) {
    auto r = __builtin_amdgcn_permlane32_swap(__float_as_int(v), __float_as_int(v),
                                              false, false);
    lo = __int_as_float(r[0]);
    hi = __int_as_float(r[1]);
}

// 16 NAMED complex scalars per g-set (never array-indexed in the hot path).
#define DECL_G(G) float2 G##0, G##1, G##2, G##3, G##4, G##5, G##6, G##7,       \
                         G##8, G##9, G##10, G##11, G##12, G##13, G##14, G##15

// g[d] = sum_ka W16^{d*ka} * mv[ka]   (W = e^{-2pi i/16}; pi-units angle d*ka/8)
#define GROW(Gd, d)                                                             \
    {   float sx = 0.0f, sy = 0.0f;                                             \
        _Pragma("unroll")                                                       \
        for (int ka = 0; ka < 16; ++ka) {                                       \
            const float ang = (float)((d) * ka) * 0.125f;                       \
            sx = fmaf(mv[ka], cospif(ang), sx);                                 \
            sy = fmaf(mv[ka], -sinpif(ang), sy);                                \
        }                                                                       \
        Gd = make_float2(sx, sy); }

#define BUILD_G(G)                                                              \
    GROW(G##0, 0)  GROW(G##1, 1)  GROW(G##2, 2)   GROW(G##3, 3)                 \
    GROW(G##4, 4)  GROW(G##5, 5)  GROW(G##6, 6)   GROW(G##7, 7)                 \
    GROW(G##8, 8)  GROW(G##9, 9)  GROW(G##10, 10) GROW(G##11, 11)               \
    GROW(G##12, 12) GROW(G##13, 13) GROW(G##14, 14) GROW(G##15, 15)

// j-th pair term: pair index (w+j)&7 holds slots a=2((w+j)&7) (.xy), a+1 (.zw).
// acc0 coeffs: g[2j] (.xy), g[2j+1] (.zw); acc1: g[(2j+15)&15] (.xy), g[2j] (.zw).
#define CTERM(G, j, A, B, C)                                                    \
    {   const float4 v = buf[par][(((w + (j)) & 7) << 6) + l];                  \
        ax0 = fmaf(G##A.x, v.x, ax0);  ax0 = fmaf(-G##A.y, v.y, ax0);           \
        ay0 = fmaf(G##A.x, v.y, ay0);  ay0 = fmaf( G##A.y, v.x, ay0);           \
        ax0 = fmaf(G##B.x, v.z, ax0);  ax0 = fmaf(-G##B.y, v.w, ax0);           \
        ay0 = fmaf(G##B.x, v.w, ay0);  ay0 = fmaf( G##B.y, v.z, ay0);           \
        ax1 = fmaf(G##C.x, v.x, ax1);  ax1 = fmaf(-G##C.y, v.y, ax1);           \
        ay1 = fmaf(G##C.x, v.y, ay1);  ay1 = fmaf( G##C.y, v.x, ay1);           \
        ax1 = fmaf(G##A.x, v.z, ax1);  ax1 = fmaf(-G##A.y, v.w, ax1);           \
        ay1 = fmaf(G##A.x, v.w, ay1);  ay1 = fmaf( G##A.y, v.z, ay1); }

// One fused exchange: pre-rotate by wt, write, barrier, 8xb128 gather, post-rotate by cw.
#define EXCHANGE_G(G)                                                           \
    do {                                                                        \
        buf[par][tt] = make_float4(wt0.x * z0.x - wt0.y * z0.y,                 \
                                   wt0.x * z0.y + wt0.y * z0.x,                 \
                                   wt1.x * z1.x - wt1.y * z1.y,                 \
                                   wt1.x * z1.y + wt1.y * z1.x);                \
        __syncthreads();                                                        \
        float ax0 = 0.0f, ay0 = 0.0f, ax1 = 0.0f, ay1 = 0.0f;                   \
        CTERM(G, 0, 0, 1, 15)   CTERM(G, 1, 2, 3, 1)                            \
        CTERM(G, 2, 4, 5, 3)    CTERM(G, 3, 6, 7, 5)                            \
        CTERM(G, 4, 8, 9, 7)    CTERM(G, 5, 10, 11, 9)                          \
        CTERM(G, 6, 12, 13, 11) CTERM(G, 7, 14, 15, 13)                         \
        z0 = make_float2(cw0.x * ax0 - cw0.y * ay0, cw0.x * ay0 + cw0.y * ax0); \
        z1 = make_float2(cw1.x * ax1 - cw1.y * ay1, cw1.x * ay1 + cw1.y * ax1); \
        par ^= 1;                                                               \
    } while (0)

__global__ __launch_bounds__(BLK, 2)
void siva_kernel(const float* __restrict__ x,
                 const float* __restrict__ nu_p,
                 const float* __restrict__ dto_p,
                 const float* __restrict__ cr_p,
                 const int* __restrict__ nt_p,
                 const int* __restrict__ ns_p,
                 float* __restrict__ out) {
    __shared__ float4 buf[2][BLK];   // parity double-buffered single exchange

    const int tt = threadIdx.x;    // 0..511
    const int b  = blockIdx.x;
    const int l  = tt & 63;
    const int w  = tt >> 6;        // wave 0..7
    const int a0 = 2 * w;          // owned slots of digit a (n = 16b + a)
    const int a1 = 2 * w + 1;
    const int kb = (int)(__brev((unsigned)l) >> 26);   // rev6(l)

    const int nT   = nt_p[0];
    const int nsub = ns_p[0];

    const float nu  = (1.0f / (1.0f + expf(-nu_p[0])))  * (0.5f - 0.01f)  + 0.01f;
    const float dto = (1.0f / (1.0f + expf(-dto_p[0]))) * (0.1f - 0.001f) + 0.001f;
    const float cR  = (1.0f / (1.0f + expf(-cr_p[0])))  * (2.0f - 0.5f)   + 0.5f;
    const float dt   = dto / (float)nsub;
    const float dtcR = dt * cR;

    // slot rotation constants: wt_p = W1024^{ap*kb}, cw_p = conj(wt_p)/1024
    float2 wt0, wt1, cw0, cw1;
    {
        const float g0a = (float)(a0 * kb) * (1.0f / 512.0f);  // pi units
        const float c0 = cospif(g0a), s0 = sinpif(g0a);
        wt0 = make_float2(c0, -s0);
        cw0 = make_float2(c0 * (1.0f / 1024.0f), s0 * (1.0f / 1024.0f));
        const float g1a = (float)(a1 * kb) * (1.0f / 512.0f);
        const float c1 = cospif(g1a), s1 = sinpif(g1a);
        wt1 = make_float2(c1, -s1);
        cw1 = make_float2(c1 * (1.0f / 1024.0f), s1 * (1.0f / 1024.0f));
    }

    // Lane-64 radix-2 tables (R2/R13 verified machinery).
    float2 wf[6]; float sg[6]; float2 wi[6];
    #pragma unroll
    for (int s = 0; s < 6; ++s) {
        const int h = 32 >> s;
        const int lm = l & (h - 1);
        const bool hif = (l & h) != 0;
        const float a = (float)(lm * (32 / h)) * (1.0f / 32.0f);   // pi units
        wf[s] = hif ? make_float2(cospif(a), -sinpif(a)) : make_float2(1.0f, 0.0f);
        sg[s] = hif ? -1.0f : 1.0f;
        const int h2 = 1 << s;
        const int lm2 = l & (h2 - 1);
        const float a2 = (float)lm2 / (float)h2;
        float2 wb = make_float2(cospif(a2), sinpif(a2));
        if ((l & h2) != 0) { wb.x = -wb.x; wb.y = -wb.y; }
        wi[s] = wb;
    }
    float2 cai[4], cbi[4];
    #pragma unroll
    for (int s = 0; s < 4; ++s) {
        const bool hif = (l & (1 << s)) != 0;
        cai[s] = hif ? wi[s] : make_float2(1.0f, 0.0f);
        cbi[s] = hif ? make_float2(1.0f, 0.0f) : wi[s];
    }

    // fwd DIF step: z = wf[s] * (partner + sg[s]*z)
    auto fwd_s = [&](float2& zz, float bx, float by, int s) {
        const float tx = fmaf(sg[s], zz.x, bx);
        const float ty = fmaf(sg[s], zz.y, by);
        zz.x = tx * wf[s].x - ty * wf[s].y;
        zz.y = tx * wf[s].y + ty * wf[s].x;
    };
    auto inv_sf = [&](float2& zz, float px, float py, int s) {
        const float nx = fmaf(cai[s].x, zz.x, fmaf(-cai[s].y, zz.y,
                         fmaf(cbi[s].x, px, -cbi[s].y * py)));
        const float ny = fmaf(cai[s].x, zz.y, fmaf(cai[s].y, zz.x,
                         fmaf(cbi[s].x, py, cbi[s].y * px)));
        zz = make_float2(nx, ny);
    };
    auto fwd_one = [&](float2& zz, int s) {
        if (s == 0) {
            float lox, hix, loy, hiy;
            pswap32(zz.x, lox, hix); pswap32(zz.y, loy, hiy);
            const float tx = fmaf(sg[0], hix, lox);
            const float ty = fmaf(sg[0], hiy, loy);
            zz.x = tx * wf[0].x - ty * wf[0].y;
            zz.y = tx * wf[0].y + ty * wf[0].x;
        } else if (s == 1) {
            float lox, hix, loy, hiy;
            pswap16(zz.x, lox, hix); pswap16(zz.y, loy, hiy);
            const float tx = fmaf(sg[1], hix, lox);
            const float ty = fmaf(sg[1], hiy, loy);
            zz.x = tx * wf[1].x - ty * wf[1].y;
            zz.y = tx * wf[1].y + ty * wf[1].x;
        } else if (s == 2) fwd_s(zz, xr8(zz.x), xr8(zz.y), 2);
        else if (s == 3)   fwd_s(zz, xr4(zz.x), xr4(zz.y), 3);
        else if (s == 4)   fwd_s(zz, qx2(zz.x), qx2(zz.y), 4);
        else               fwd_s(zz, qx1(zz.x), qx1(zz.y), 5);
    };
    auto inv_one = [&](float2& zz, int s) {
        if (s == 0)      inv_sf(zz, qx1(zz.x), qx1(zz.y), 0);
        else if (s == 1) inv_sf(zz, qx2(zz.x), qx2(zz.y), 1);
        else if (s == 2) inv_sf(zz, xr4(zz.x), xr4(zz.y), 2);
        else if (s == 3) inv_sf(zz, xr8(zz.x), xr8(zz.y), 3);
        else if (s == 4) {
            float lox, hix, loy, hiy;
            pswap16(zz.x, lox, hix); pswap16(zz.y, loy, hiy);
            zz.x = fmaf(wi[4].x, hix, fmaf(-wi[4].y, hiy, lox));
            zz.y = fmaf(wi[4].x, hiy, fmaf( wi[4].y, hix, loy));
        } else {
            float lox, hix, loy, hiy;
            pswap32(zz.x, lox, hix); pswap32(zz.y, loy, hiy);
            zz.x = fmaf(wi[5].x, hix, fmaf(-wi[5].y, hiy, lox));
            zz.y = fmaf(wi[5].x, hiy, fmaf( wi[5].y, hix, loy));
        }
    };
    auto lane_fwd6 = [&](float2& za, float2& zb) {
        #pragma unroll
        for (int s = 0; s < 6; ++s) { fwd_one(za, s); fwd_one(zb, s); }
    };
    auto lane_inv6 = [&](float2& za, float2& zb) {
        #pragma unroll
        for (int s = 0; s < 6; ++s) { inv_one(za, s); inv_one(zb, s); }
    };

    // ---- substep g-set (hot, named scalars) ----
    DECL_G(gS);
    {
        float mv[16];
        #pragma unroll
        for (int ka = 0; ka < 16; ++ka) {
            const int k = kb + 64 * ka;
            const float kk = (k <= 512) ? (float)k : (float)(k - 1024);
            const float kab = fabsf(kk);
            const float q = 1.0f - dtcR * (kab - nu * kab * kab);
            const float kkS = (k == 0 || k == 512) ? 0.0f : kk;
            mv[ka] = (1.0f - dt * kkS) / q;
        }
        BUILD_G(gS)
    }

    int par = 0;
    float2 z0, z1;
    float u0, u1;

    // ---- init: d_to_u.  u = -Im(composite with m = kk) ----
    z0 = make_float2(x[b * NFFT + 16 * l + a0], 0.0f);
    z1 = make_float2(x[b * NFFT + 16 * l + a1], 0.0f);
    {
        DECL_G(gD);
        {
            float mv[16];
            #pragma unroll
            for (int ka = 0; ka < 16; ++ka) {
                const int k = kb + 64 * ka;
                mv[ka] = (k <= 512) ? (float)k : (float)(k - 1024);
            }
            BUILD_G(gD)
        }
        lane_fwd6(z0, z1);
        EXCHANGE_G(gD);
        lane_inv6(z0, z1);
        u0 = -z0.y;
        u1 = -z1.y;
    }

    for (int ot = 0; ot < nT; ++ot) {
        for (int ss = 0; ss < nsub; ++ss) {
            z0 = make_float2(u0, 0.5f * u0 * u0);
            z1 = make_float2(u1, 0.5f * u1 * u1);
            lane_fwd6(z0, z1);
            EXCHANGE_G(gS);   // fused: DFT16 + twiddles + S + invDFT16
            lane_inv6(z0, z1);
            u0 = z0.x;        // Re
            u1 = z1.x;
        }
        // snapshot: u_to_d. out = +Im(composite with m = 1/kk)
        {
            DECL_G(gU);
            {
                float mv[16];
                #pragma unroll
                for (int ka = 0; ka < 16; ++ka) {
                    const int k = kb + 64 * ka;
                    const float kk = (k <= 512) ? (float)k : (float)(k - 1024);
                    mv[ka] = (k == 0) ? 0.0f : (1.0f / kk);
                }
                BUILD_G(gU)
            }
            z0 = make_float2(u0, 0.0f);
            z1 = make_float2(u1, 0.0f);
            lane_fwd6(z0, z1);
            EXCHANGE_G(gU);
            lane_inv6(z0, z1);
            out[(b * NFFT + 16 * l + a0) * nT + ot] = z0.y;  // Im
            out[(b * NFFT + 16 * l + a1) * nT + ot] = z1.y;
        }
    }
}

extern "C" void kernel_launch(void* const* d_in, const int* in_sizes, int n_in,
                              void* d_out, int out_size, void* d_ws, size_t ws_size,
                              hipStream_t stream) {
    const float* x     = (const float*)d_in[0];
    const float* nu_p  = (const float*)d_in[1];
    const float* dto_p = (const float*)d_in[2];
    const float* cr_p  = (const float*)d_in[3];
    const int*   nt_p  = (const int*)d_in[4];
    const int*   ns_p  = (const int*)d_in[5];
    float* out = (float*)d_out;

    const int B = in_sizes[0] / NFFT;  // C == 1
    siva_kernel<<<B, BLK, 0, stream>>>(x, nu_p, dto_p, cr_p, nt_p, ns_p, out);
}

// Round 17
// 665.523 us; speedup vs baseline: 3.9854x; 1.0719x over previous
//
#include <hip/hip_runtime.h>
#include <math.h>

#define NFFT 1024
#define BLK  512   // 8 waves, ONE batch per block; grid = 128

// ---- DPP cross-lane (VALU pipe), HW-validated R6/R10 ----
template <int CTRL>
__device__ __forceinline__ float dppf(float v) {
    return __int_as_float(__builtin_amdgcn_update_dpp(
        0, __float_as_int(v), CTRL, 0xF, 0xF, true));
}
__device__ __forceinline__ float qx1(float v) { return dppf<0xB1>(v); }   // l^1
__device__ __forceinline__ float qx2(float v) { return dppf<0x4E>(v); }   // l^2
__device__ __forceinline__ float xr4(float v) { return dppf<0x1B>(dppf<0x141>(v)); } // l^4
__device__ __forceinline__ float xr8(float v) { return dppf<0x128>(v); }  // l^8

__device__ __forceinline__ void pswap16(float v, float& lo, float& hi) {
    auto r = __builtin_amdgcn_permlane16_swap(__float_as_int(v), __float_as_int(v),
                                              false, false);
    lo = __int_as_float(r[0]);
    hi = __int_as_float(r[1]);
}
__device__ __forceinline__ void pswap32(float v, float& lo, float& hi) {
    auto r = __builtin_amdgcn_permlane32_swap(__float_as_int(v), __float_as_int(v),
                                              false, false);
    lo = __int_as_float(r[0]);
    hi = __int_as_float(r[1]);
}

// 8 NAMED complex scalars per g-set (never array-indexed in the hot path).
#define DECL_G8(G) float2 G##0, G##1, G##2, G##3, G##4, G##5, G##6, G##7

// g[d] = sum_{ka<8} W8^{d*ka} * mv[ka]   (W8 angle pi-units: d*ka/4)
#define GROW8(Gd, d)                                                            \
    {   float sx = 0.0f, sy = 0.0f;                                             \
        _Pragma("unroll")                                                       \
        for (int ka = 0; ka < 8; ++ka) {                                        \
            const float ang = (float)((d) * ka) * 0.25f;                        \
            sx = fmaf(mv[ka], cospif(ang), sx);                                 \
            sy = fmaf(mv[ka], -sinpif(ang), sy);                                \
        }                                                                       \
        Gd = make_float2(sx, sy); }

#define BUILD_G8(G)                                                             \
    GROW8(G##0, 0) GROW8(G##1, 1) GROW8(G##2, 2) GROW8(G##3, 3)                 \
    GROW8(G##4, 4) GROW8(G##5, 5) GROW8(G##6, 6) GROW8(G##7, 7)

// term j: slot a'=(w+j)&7; reg0 uses GA##j on (v.x,v.y), reg1 GB##j on (v.z,v.w)
#define CT8(GA, GB, j)                                                          \
    {   const float4 v = buf[par][(((w + (j)) & 7) << 6) + l];                  \
        ax0 = fmaf(GA##j.x, v.x, ax0);  ax0 = fmaf(-GA##j.y, v.y, ax0);         \
        ay0 = fmaf(GA##j.x, v.y, ay0);  ay0 = fmaf( GA##j.y, v.x, ay0);         \
        ax1 = fmaf(GB##j.x, v.z, ax1);  ax1 = fmaf(-GB##j.y, v.w, ax1);         \
        ay1 = fmaf(GB##j.x, v.w, ay1);  ay1 = fmaf( GB##j.y, v.z, ay1); }

// One fused exchange (pre/post rotations folded into adjacent lane stages).
#define EXCHANGE8(GA, GB)                                                       \
    do {                                                                        \
        buf[par][tt] = make_float4(z0.x, z0.y, z1.x, z1.y);                     \
        __syncthreads();                                                        \
        float ax0 = 0.0f, ay0 = 0.0f, ax1 = 0.0f, ay1 = 0.0f;                   \
        CT8(GA, GB, 0) CT8(GA, GB, 1) CT8(GA, GB, 2) CT8(GA, GB, 3)             \
        CT8(GA, GB, 4) CT8(GA, GB, 5) CT8(GA, GB, 6) CT8(GA, GB, 7)             \
        z0 = make_float2(ax0, ay0);                                             \
        z1 = make_float2(ax1, ay1);                                             \
        par ^= 1;                                                               \
    } while (0)

__global__ __launch_bounds__(BLK, 2)
void siva_kernel(const float* __restrict__ x,
                 const float* __restrict__ nu_p,
                 const float* __restrict__ dto_p,
                 const float* __restrict__ cr_p,
                 const int* __restrict__ nt_p,
                 const int* __restrict__ ns_p,
                 float* __restrict__ out) {
    __shared__ float4 buf[2][BLK];   // parity double-buffered single exchange

    const int tt = threadIdx.x;    // 0..511
    const int b  = blockIdx.x;
    const int l  = tt & 63;
    const int w  = tt >> 6;        // wave 0..7 = slot digit a (n = 8*b128 + a)
    const int R  = (int)(__brev((unsigned)l) >> 26);   // rev6(l)
    const int kb0 = 2 * R;         // reg0 spectral line (even)
    const int kb1 = 2 * R + 1;     // reg1 spectral line (odd)

    const int nT   = nt_p[0];
    const int nsub = ns_p[0];

    const float nu  = (1.0f / (1.0f + expf(-nu_p[0])))  * (0.5f - 0.01f)  + 0.01f;
    const float dto = (1.0f / (1.0f + expf(-dto_p[0]))) * (0.1f - 0.001f) + 0.001f;
    const float cR  = (1.0f / (1.0f + expf(-cr_p[0])))  * (2.0f - 0.5f)   + 0.5f;
    const float dt   = dto / (float)nsub;
    const float dtcR = dt * cR;

    // reg radix-2 twiddle W128^{l} and its conjugate (inverse side)
    float2 T128, cT128;
    { const float a = (float)l * (1.0f / 64.0f);   // pi units
      const float c = cospif(a), s = sinpif(a);
      T128  = make_float2(c, -s);
      cT128 = make_float2(c,  s); }

    // fwd stage-5 fold: wtF_r = W1024^{w*kb_r}  (replaces trivial (1,0) twiddle)
    float2 wtF0, wtF1;
    // inv stage-0 fold: Cai0_r = (+-1)*conj(wtF_r)/1024, Cbi0_r = conj(wt at lane l^1)/1024
    float2 Cai0_0, Cai0_1, Cbi0_0, Cbi0_1;
    {
        const float sgn1 = (l & 1) ? -1.0f : 1.0f;
        const float a0a = (float)(w * kb0) * (1.0f / 512.0f);
        const float a1a = (float)(w * kb1) * (1.0f / 512.0f);
        wtF0 = make_float2(cospif(a0a), -sinpif(a0a));
        wtF1 = make_float2(cospif(a1a), -sinpif(a1a));
        Cai0_0 = make_float2(sgn1 * cospif(a0a) * (1.0f / 1024.0f),
                             sgn1 * sinpif(a0a) * (1.0f / 1024.0f));
        Cai0_1 = make_float2(sgn1 * cospif(a1a) * (1.0f / 1024.0f),
                             sgn1 * sinpif(a1a) * (1.0f / 1024.0f));
        const int Rp = R ^ 32;                     // rev6(l^1)
        const float p0a = (float)(w * (2 * Rp)) * (1.0f / 512.0f);
        const float p1a = (float)(w * (2 * Rp + 1)) * (1.0f / 512.0f);
        Cbi0_0 = make_float2(cospif(p0a) * (1.0f / 1024.0f),
                             sinpif(p0a) * (1.0f / 1024.0f));
        Cbi0_1 = make_float2(cospif(p1a) * (1.0f / 1024.0f),
                             sinpif(p1a) * (1.0f / 1024.0f));
    }

    // Lane-64 radix-2 tables (R2/R13 verified machinery). Stage 5 fwd / 0 inv folded.
    float2 wf[5]; float sg[5]; float2 wi[6];
    #pragma unroll
    for (int s = 0; s < 6; ++s) {
        const int h = 32 >> s;
        const int lm = l & (h - 1);
        const bool hif = (l & h) != 0;
        if (s < 5) {
            const float a = (float)(lm * (32 / h)) * (1.0f / 32.0f);   // pi units
            wf[s] = hif ? make_float2(cospif(a), -sinpif(a)) : make_float2(1.0f, 0.0f);
            sg[s] = hif ? -1.0f : 1.0f;
        }
        const int h2 = 1 << s;
        const int lm2 = l & (h2 - 1);
        const float a2 = (float)lm2 / (float)h2;
        float2 wb = make_float2(cospif(a2), sinpif(a2));
        if ((l & h2) != 0) { wb.x = -wb.x; wb.y = -wb.y; }
        wi[s] = wb;
    }
    const float sg5 = (l & 1) ? -1.0f : 1.0f;
    // select-free inverse butterflies for DPP stages s=1..3 (h=2,4,8)
    float2 cai[4], cbi[4];
    #pragma unroll
    for (int s = 1; s < 4; ++s) {
        const bool hif = (l & (1 << s)) != 0;
        cai[s] = hif ? wi[s] : make_float2(1.0f, 0.0f);
        cbi[s] = hif ? make_float2(1.0f, 0.0f) : wi[s];
    }

    // fwd DIF step: z = wf[s] * (partner + sg[s]*z)
    auto fwd_s = [&](float2& zz, float bx, float by, int s) {
        const float tx = fmaf(sg[s], zz.x, bx);
        const float ty = fmaf(sg[s], zz.y, by);
        zz.x = tx * wf[s].x - ty * wf[s].y;
        zz.y = tx * wf[s].y + ty * wf[s].x;
    };
    auto inv_sf = [&](float2& zz, float px, float py, int s) {
        const float nx = fmaf(cai[s].x, zz.x, fmaf(-cai[s].y, zz.y,
                         fmaf(cbi[s].x, px, -cbi[s].y * py)));
        const float ny = fmaf(cai[s].x, zz.y, fmaf(cai[s].y, zz.x,
                         fmaf(cbi[s].x, py, cbi[s].y * px)));
        zz = make_float2(nx, ny);
    };

    // fwd: reg radix-2 (stride 64) then lane stages 0..4 then folded h=1 stage
    auto fwd_all = [&](float2& z0, float2& z1) {
        // reg stage: A = z0+z1 ; B = (z0-z1)*T128
        {
            const float dxr = z0.x - z1.x, dyr = z0.y - z1.y;
            z0 = make_float2(z0.x + z1.x, z0.y + z1.y);
            z1 = make_float2(dxr * T128.x - dyr * T128.y,
                             dxr * T128.y + dyr * T128.x);
        }
        // lane stages h=32,16 (permlane) + 8,4,2 (DPP)
        {
            float lox, hix, loy, hiy;
            pswap32(z0.x, lox, hix); pswap32(z0.y, loy, hiy);
            float tx = fmaf(sg[0], hix, lox), ty = fmaf(sg[0], hiy, loy);
            z0.x = tx * wf[0].x - ty * wf[0].y;
            z0.y = tx * wf[0].y + ty * wf[0].x;
            pswap32(z1.x, lox, hix); pswap32(z1.y, loy, hiy);
            tx = fmaf(sg[0], hix, lox); ty = fmaf(sg[0], hiy, loy);
            z1.x = tx * wf[0].x - ty * wf[0].y;
            z1.y = tx * wf[0].y + ty * wf[0].x;
        }
        {
            float lox, hix, loy, hiy;
            pswap16(z0.x, lox, hix); pswap16(z0.y, loy, hiy);
            float tx = fmaf(sg[1], hix, lox), ty = fmaf(sg[1], hiy, loy);
            z0.x = tx * wf[1].x - ty * wf[1].y;
            z0.y = tx * wf[1].y + ty * wf[1].x;
            pswap16(z1.x, lox, hix); pswap16(z1.y, loy, hiy);
            tx = fmaf(sg[1], hix, lox); ty = fmaf(sg[1], hiy, loy);
            z1.x = tx * wf[1].x - ty * wf[1].y;
            z1.y = tx * wf[1].y + ty * wf[1].x;
        }
        fwd_s(z0, xr8(z0.x), xr8(z0.y), 2);  fwd_s(z1, xr8(z1.x), xr8(z1.y), 2);
        fwd_s(z0, xr4(z0.x), xr4(z0.y), 3);  fwd_s(z1, xr4(z1.x), xr4(z1.y), 3);
        fwd_s(z0, qx2(z0.x), qx2(z0.y), 4);  fwd_s(z1, qx2(z1.x), qx2(z1.y), 4);
        // folded h=1 stage: z = wtF_r * (partner + sg5*z)   (wf5 == (1,0) absorbed wt)
        {
            const float px = qx1(z0.x), py = qx1(z0.y);
            const float tx = fmaf(sg5, z0.x, px), ty = fmaf(sg5, z0.y, py);
            z0.x = tx * wtF0.x - ty * wtF0.y;
            z0.y = tx * wtF0.y + ty * wtF0.x;
        }
        {
            const float px = qx1(z1.x), py = qx1(z1.y);
            const float tx = fmaf(sg5, z1.x, px), ty = fmaf(sg5, z1.y, py);
            z1.x = tx * wtF1.x - ty * wtF1.y;
            z1.y = tx * wtF1.y + ty * wtF1.x;
        }
    };

    // inv: folded h=1 stage (carries conj(wt)/1024), stages 1..5, reg combine
    auto inv_all = [&](float2& z0, float2& z1) {
        // folded stage 0: out = Cai0_r*own + Cbi0_r*partner
        {
            const float px = qx1(z0.x), py = qx1(z0.y);
            const float nx = fmaf(Cai0_0.x, z0.x, fmaf(-Cai0_0.y, z0.y,
                             fmaf(Cbi0_0.x, px, -Cbi0_0.y * py)));
            const float ny = fmaf(Cai0_0.x, z0.y, fmaf(Cai0_0.y, z0.x,
                             fmaf(Cbi0_0.x, py, Cbi0_0.y * px)));
            z0 = make_float2(nx, ny);
        }
        {
            const float px = qx1(z1.x), py = qx1(z1.y);
            const float nx = fmaf(Cai0_1.x, z1.x, fmaf(-Cai0_1.y, z1.y,
                             fmaf(Cbi0_1.x, px, -Cbi0_1.y * py)));
            const float ny = fmaf(Cai0_1.x, z1.y, fmaf(Cai0_1.y, z1.x,
                             fmaf(Cbi0_1.x, py, Cbi0_1.y * px)));
            z1 = make_float2(nx, ny);
        }
        inv_sf(z0, qx2(z0.x), qx2(z0.y), 1);  inv_sf(z1, qx2(z1.x), qx2(z1.y), 1);
        inv_sf(z0, xr4(z0.x), xr4(z0.y), 2);  inv_sf(z1, xr4(z1.x), xr4(z1.y), 2);
        inv_sf(z0, xr8(z0.x), xr8(z0.y), 3);  inv_sf(z1, xr8(z1.x), xr8(z1.y), 3);
        {
            float lox, hix, loy, hiy;
            pswap16(z0.x, lox, hix); pswap16(z0.y, loy, hiy);
            z0.x = fmaf(wi[4].x, hix, fmaf(-wi[4].y, hiy, lox));
            z0.y = fmaf(wi[4].x, hiy, fmaf( wi[4].y, hix, loy));
            pswap16(z1.x, lox, hix); pswap16(z1.y, loy, hiy);
            z1.x = fmaf(wi[4].x, hix, fmaf(-wi[4].y, hiy, lox));
            z1.y = fmaf(wi[4].x, hiy, fmaf( wi[4].y, hix, loy));
        }
        {
            float lox, hix, loy, hiy;
            pswap32(z0.x, lox, hix); pswap32(z0.y, loy, hiy);
            z0.x = fmaf(wi[5].x, hix, fmaf(-wi[5].y, hiy, lox));
            z0.y = fmaf(wi[5].x, hiy, fmaf( wi[5].y, hix, loy));
            pswap32(z1.x, lox, hix); pswap32(z1.y, loy, hiy);
            z1.x = fmaf(wi[5].x, hix, fmaf(-wi[5].y, hiy, lox));
            z1.y = fmaf(wi[5].x, hiy, fmaf( wi[5].y, hix, loy));
        }
        // reg combine: tmp = cT128*z1; out0 = z0+tmp (b=l), out1 = z0-tmp (b=64+l)
        {
            const float tx = z1.x * cT128.x - z1.y * cT128.y;
            const float ty = z1.x * cT128.y + z1.y * cT128.x;
            z1 = make_float2(z0.x - tx, z0.y - ty);
            z0 = make_float2(z0.x + tx, z0.y + ty);
        }
    };

    // ---- substep g-sets (hot, named scalars; per spectral line kb0/kb1) ----
    DECL_G8(gS0); DECL_G8(gS1);
    {
        float mv[8];
        #pragma unroll
        for (int ka = 0; ka < 8; ++ka) {
            const int k = kb0 + 128 * ka;
            const float kk = (k <= 512) ? (float)k : (float)(k - 1024);
            const float kab = fabsf(kk);
            const float q = 1.0f - dtcR * (kab - nu * kab * kab);
            const float kkS = (k == 0 || k == 512) ? 0.0f : kk;
            mv[ka] = (1.0f - dt * kkS) / q;
        }
        BUILD_G8(gS0)
    }
    {
        float mv[8];
        #pragma unroll
        for (int ka = 0; ka < 8; ++ka) {
            const int k = kb1 + 128 * ka;
            const float kk = (k <= 512) ? (float)k : (float)(k - 1024);
            const float kab = fabsf(kk);
            const float q = 1.0f - dtcR * (kab - nu * kab * kab);
            const float kkS = (k == 0 || k == 512) ? 0.0f : kk;
            mv[ka] = (1.0f - dt * kkS) / q;
        }
        BUILD_G8(gS1)
    }

    int par = 0;
    float2 z0, z1;
    float u0, u1;
    const int n0 = 8 * l + w;        // point of reg0 (b=l)
    const int n1 = 512 + 8 * l + w;  // point of reg1 (b=64+l)

    // ---- init: d_to_u.  u = -Im(composite with m = kk) ----
    z0 = make_float2(x[b * NFFT + n0], 0.0f);
    z1 = make_float2(x[b * NFFT + n1], 0.0f);
    {
        DECL_G8(gD0); DECL_G8(gD1);
        {
            float mv[8];
            #pragma unroll
            for (int ka = 0; ka < 8; ++ka) {
                const int k = kb0 + 128 * ka;
                mv[ka] = (k <= 512) ? (float)k : (float)(k - 1024);
            }
            BUILD_G8(gD0)
        }
        {
            float mv[8];
            #pragma unroll
            for (int ka = 0; ka < 8; ++ka) {
                const int k = kb1 + 128 * ka;
                mv[ka] = (k <= 512) ? (float)k : (float)(k - 1024);
            }
            BUILD_G8(gD1)
        }
        fwd_all(z0, z1);
        EXCHANGE8(gD0, gD1);
        inv_all(z0, z1);
        u0 = -z0.y;
        u1 = -z1.y;
    }

    for (int ot = 0; ot < nT; ++ot) {
        for (int ss = 0; ss < nsub; ++ss) {
            z0 = make_float2(u0, 0.5f * u0 * u0);
            z1 = make_float2(u1, 0.5f * u1 * u1);
            fwd_all(z0, z1);
            EXCHANGE8(gS0, gS1);   // fused: DFT8 + twiddles + S + invDFT8
            inv_all(z0, z1);
            u0 = z0.x;             // Re
            u1 = z1.x;
        }
        // snapshot: u_to_d. out = +Im(composite with m = 1/kk)
        {
            DECL_G8(gU0); DECL_G8(gU1);
            {
                float mv[8];
                #pragma unroll
                for (int ka = 0; ka < 8; ++ka) {
                    const int k = kb0 + 128 * ka;
                    const float kk = (k <= 512) ? (float)k : (float)(k - 1024);
                    mv[ka] = (k == 0) ? 0.0f : (1.0f / kk);
                }
                BUILD_G8(gU0)
            }
            {
                float mv[8];
                #pragma unroll
                for (int ka = 0; ka < 8; ++ka) {
                    const int k = kb1 + 128 * ka;
                    const float kk = (k <= 512) ? (float)k : (float)(k - 1024);
                    mv[ka] = (k == 0) ? 0.0f : (1.0f / kk);
                }
                BUILD_G8(gU1)
            }
            z0 = make_float2(u0, 0.0f);
            z1 = make_float2(u1, 0.0f);
            fwd_all(z0, z1);
            EXCHANGE8(gU0, gU1);
            inv_all(z0, z1);
            out[(b * NFFT + n0) * nT + ot] = z0.y;  // Im
            out[(b * NFFT + n1) * nT + ot] = z1.y;
        }
    }
}

extern "C" void kernel_launch(void* const* d_in, const int* in_sizes, int n_in,
                              void* d_out, int out_size, void* d_ws, size_t ws_size,
                              hipStream_t stream) {
    const float* x     = (const float*)d_in[0];
    const float* nu_p  = (const float*)d_in[1];
    const float* dto_p = (const float*)d_in[2];
    const float* cr_p  = (const float*)d_in[3];
    const int*   nt_p  = (const int*)d_in[4];
    const int*   ns_p  = (const int*)d_in[5];
    float* out = (float*)d_out;

    const int B = in_sizes[0] / NFFT;  // C == 1
    siva_kernel<<<B, BLK, 0, stream>>>(x, nu_p, dto_p, cr_p, nt_p, ns_p, out);
}

// Round 18
// 653.428 us; speedup vs baseline: 4.0592x; 1.0185x over previous
//
#include <hip/hip_runtime.h>
#include <math.h>

#define NFFT 1024
#define BLK  512   // 8 waves, ONE batch per block; grid = 128

// ---- DPP cross-lane (VALU pipe), HW-validated R6/R10 ----
template <int CTRL>
__device__ __forceinline__ float dppf(float v) {
    return __int_as_float(__builtin_amdgcn_update_dpp(
        0, __float_as_int(v), CTRL, 0xF, 0xF, true));
}
__device__ __forceinline__ float qx1(float v) { return dppf<0xB1>(v); }   // l^1
__device__ __forceinline__ float qx2(float v) { return dppf<0x4E>(v); }   // l^2
__device__ __forceinline__ float xr4(float v) { return dppf<0x1B>(dppf<0x141>(v)); } // l^4
__device__ __forceinline__ float xr8(float v) { return dppf<0x128>(v); }  // l^8

__device__ __forceinline__ void pswap16(float v, float& lo, float& hi) {
    auto r = __builtin_amdgcn_permlane16_swap(__float_as_int(v), __float_as_int(v),
                                              false, false);
    lo = __int_as_float(r[0]);
    hi = __int_as_float(r[1]);
}
__device__ __forceinline__ void pswap32(float v, float& lo, float& hi) {
    auto r = __builtin_amdgcn_permlane32_swap(__float_as_int(v), __float_as_int(v),
                                              false, false);
    lo = __int_as_float(r[0]);
    hi = __int_as_float(r[1]);
}

// 8 NAMED complex scalars per g-set (never array-indexed in the hot path).
#define DECL_G8(G) float2 G##0, G##1, G##2, G##3, G##4, G##5, G##6, G##7

// g[d] = sum_{ka<8} W8^{d*ka} * mv[ka]   (W8 angle pi-units: d*ka/4)
#define GROW8(Gd, d)                                                            \
    {   float sx = 0.0f, sy = 0.0f;                                             \
        _Pragma("unroll")                                                       \
        for (int ka = 0; ka < 8; ++ka) {                                        \
            const float ang = (float)((d) * ka) * 0.25f;                        \
            sx = fmaf(mv[ka], cospif(ang), sx);                                 \
            sy = fmaf(mv[ka], -sinpif(ang), sy);                                \
        }                                                                       \
        Gd = make_float2(sx, sy); }

#define BUILD_G8(G)                                                             \
    GROW8(G##0, 0) GROW8(G##1, 1) GROW8(G##2, 2) GROW8(G##3, 3)                 \
    GROW8(G##4, 4) GROW8(G##5, 5) GROW8(G##6, 6) GROW8(G##7, 7)

// term j (complex coeff): slot a'=(w+j)&7
#define CT8(GA, GB, j)                                                          \
    {   const float4 v = buf[par][(((w + (j)) & 7) << 6) + l];                  \
        ax0 = fmaf(GA##j.x, v.x, ax0);  ax0 = fmaf(-GA##j.y, v.y, ax0);         \
        ay0 = fmaf(GA##j.x, v.y, ay0);  ay0 = fmaf( GA##j.y, v.x, ay0);         \
        ax1 = fmaf(GB##j.x, v.z, ax1);  ax1 = fmaf(-GB##j.y, v.w, ax1);         \
        ay1 = fmaf(GB##j.x, v.w, ay1);  ay1 = fmaf( GB##j.y, v.z, ay1); }

// term j with EXACTLY-REAL coefficient (j=0: sinpif(0)=0; j=4: sinpif(int)=0)
#define CT8R(GA, GB, j)                                                         \
    {   const float4 v = buf[par][(((w + (j)) & 7) << 6) + l];                  \
        ax0 = fmaf(GA##j.x, v.x, ax0);  ay0 = fmaf(GA##j.x, v.y, ay0);          \
        ax1 = fmaf(GB##j.x, v.z, ax1);  ay1 = fmaf(GB##j.x, v.w, ay1); }

// One fused exchange (rotations folded into adjacent lane stages).
#define EXCHANGE8(GA, GB)                                                       \
    do {                                                                        \
        buf[par][tt] = make_float4(z0.x, z0.y, z1.x, z1.y);                     \
        __syncthreads();                                                        \
        float ax0 = 0.0f, ay0 = 0.0f, ax1 = 0.0f, ay1 = 0.0f;                   \
        CT8R(GA, GB, 0) CT8(GA, GB, 1) CT8(GA, GB, 2) CT8(GA, GB, 3)            \
        CT8R(GA, GB, 4) CT8(GA, GB, 5) CT8(GA, GB, 6) CT8(GA, GB, 7)            \
        z0 = make_float2(ax0, ay0);                                             \
        z1 = make_float2(ax1, ay1);                                             \
        par ^= 1;                                                               \
    } while (0)

__global__ __launch_bounds__(BLK, 2)
void siva_kernel(const float* __restrict__ x,
                 const float* __restrict__ nu_p,
                 const float* __restrict__ dto_p,
                 const float* __restrict__ cr_p,
                 const int* __restrict__ nt_p,
                 const int* __restrict__ ns_p,
                 float* __restrict__ out) {
    __shared__ float4 buf[2][BLK];   // parity double-buffered single exchange

    const int tt = threadIdx.x;    // 0..511
    const int b  = blockIdx.x;
    const int l  = tt & 63;
    const int w  = tt >> 6;        // wave 0..7 = slot digit a (n = 8*b128 + a)
    const int R  = (int)(__brev((unsigned)l) >> 26);   // rev6(l)
    const int kb0 = 2 * R;         // reg0 spectral line (even)
    const int kb1 = 2 * R + 1;     // reg1 spectral line (odd)

    const int nT   = nt_p[0];
    const int nsub = ns_p[0];

    const float nu  = (1.0f / (1.0f + expf(-nu_p[0])))  * (0.5f - 0.01f)  + 0.01f;
    const float dto = (1.0f / (1.0f + expf(-dto_p[0]))) * (0.1f - 0.001f) + 0.001f;
    const float cR  = (1.0f / (1.0f + expf(-cr_p[0])))  * (2.0f - 0.5f)   + 0.5f;
    const float dt   = dto / (float)nsub;
    const float dtcR = dt * cR;

    // reg radix-2 twiddle W128^{l} and its conjugate (inverse side)
    float2 T128, cT128;
    { const float a = (float)l * (1.0f / 64.0f);   // pi units
      const float c = cospif(a), s = sinpif(a);
      T128  = make_float2(c, -s);
      cT128 = make_float2(c,  s); }

    // fwd stage-5 fold: wtF_r = W1024^{w*kb_r}
    float2 wtF0, wtF1;
    // inv stage-0 fold: Cai0_r = (+-1)*conj(wtF_r)/1024, Cbi0_r = conj(wt at l^1)/1024
    float2 Cai0_0, Cai0_1, Cbi0_0, Cbi0_1;
    {
        const float sgn1 = (l & 1) ? -1.0f : 1.0f;
        const float a0a = (float)(w * kb0) * (1.0f / 512.0f);
        const float a1a = (float)(w * kb1) * (1.0f / 512.0f);
        wtF0 = make_float2(cospif(a0a), -sinpif(a0a));
        wtF1 = make_float2(cospif(a1a), -sinpif(a1a));
        Cai0_0 = make_float2(sgn1 * cospif(a0a) * (1.0f / 1024.0f),
                             sgn1 * sinpif(a0a) * (1.0f / 1024.0f));
        Cai0_1 = make_float2(sgn1 * cospif(a1a) * (1.0f / 1024.0f),
                             sgn1 * sinpif(a1a) * (1.0f / 1024.0f));
        const int Rp = R ^ 32;                     // rev6(l^1)
        const float p0a = (float)(w * (2 * Rp)) * (1.0f / 512.0f);
        const float p1a = (float)(w * (2 * Rp + 1)) * (1.0f / 512.0f);
        Cbi0_0 = make_float2(cospif(p0a) * (1.0f / 1024.0f),
                             sinpif(p0a) * (1.0f / 1024.0f));
        Cbi0_1 = make_float2(cospif(p1a) * (1.0f / 1024.0f),
                             sinpif(p1a) * (1.0f / 1024.0f));
    }

    // Lane-64 radix-2 tables (R2/R13 verified). Stage 5 fwd / 0 inv folded.
    float2 wf[5]; float sg[5]; float2 wi[6];
    #pragma unroll
    for (int s = 0; s < 6; ++s) {
        const int h = 32 >> s;
        const int lm = l & (h - 1);
        const bool hif = (l & h) != 0;
        if (s < 5) {
            const float a = (float)(lm * (32 / h)) * (1.0f / 32.0f);   // pi units
            wf[s] = hif ? make_float2(cospif(a), -sinpif(a)) : make_float2(1.0f, 0.0f);
            sg[s] = hif ? -1.0f : 1.0f;
        }
        const int h2 = 1 << s;
        const int lm2 = l & (h2 - 1);
        const float a2 = (float)lm2 / (float)h2;
        float2 wb = make_float2(cospif(a2), sinpif(a2));
        if ((l & h2) != 0) { wb.x = -wb.x; wb.y = -wb.y; }
        wi[s] = wb;
    }
    const float sg5 = (l & 1) ? -1.0f : 1.0f;
    float2 cai[4], cbi[4];
    #pragma unroll
    for (int s = 1; s < 4; ++s) {
        const bool hif = (l & (1 << s)) != 0;
        cai[s] = hif ? wi[s] : make_float2(1.0f, 0.0f);
        cbi[s] = hif ? make_float2(1.0f, 0.0f) : wi[s];
    }

    auto fwd_s = [&](float2& zz, float bx, float by, int s) {
        const float tx = fmaf(sg[s], zz.x, bx);
        const float ty = fmaf(sg[s], zz.y, by);
        zz.x = tx * wf[s].x - ty * wf[s].y;
        zz.y = tx * wf[s].y + ty * wf[s].x;
    };
    auto inv_sf = [&](float2& zz, float px, float py, int s) {
        const float nx = fmaf(cai[s].x, zz.x, fmaf(-cai[s].y, zz.y,
                         fmaf(cbi[s].x, px, -cbi[s].y * py)));
        const float ny = fmaf(cai[s].x, zz.y, fmaf(cai[s].y, zz.x,
                         fmaf(cbi[s].x, py, cbi[s].y * px)));
        zz = make_float2(nx, ny);
    };

    // fwd: reg radix-2 then lane stages 0..4 then folded h=1 stage (R17-verified)
    auto fwd_all = [&](float2& z0, float2& z1) {
        {
            const float dxr = z0.x - z1.x, dyr = z0.y - z1.y;
            z0 = make_float2(z0.x + z1.x, z0.y + z1.y);
            z1 = make_float2(dxr * T128.x - dyr * T128.y,
                             dxr * T128.y + dyr * T128.x);
        }
        {
            float lox, hix, loy, hiy;
            pswap32(z0.x, lox, hix); pswap32(z0.y, loy, hiy);
            float tx = fmaf(sg[0], hix, lox), ty = fmaf(sg[0], hiy, loy);
            z0.x = tx * wf[0].x - ty * wf[0].y;
            z0.y = tx * wf[0].y + ty * wf[0].x;
            pswap32(z1.x, lox, hix); pswap32(z1.y, loy, hiy);
            tx = fmaf(sg[0], hix, lox); ty = fmaf(sg[0], hiy, loy);
            z1.x = tx * wf[0].x - ty * wf[0].y;
            z1.y = tx * wf[0].y + ty * wf[0].x;
        }
        {
            float lox, hix, loy, hiy;
            pswap16(z0.x, lox, hix); pswap16(z0.y, loy, hiy);
            float tx = fmaf(sg[1], hix, lox), ty = fmaf(sg[1], hiy, loy);
            z0.x = tx * wf[1].x - ty * wf[1].y;
            z0.y = tx * wf[1].y + ty * wf[1].x;
            pswap16(z1.x, lox, hix); pswap16(z1.y, loy, hiy);
            tx = fmaf(sg[1], hix, lox); ty = fmaf(sg[1], hiy, loy);
            z1.x = tx * wf[1].x - ty * wf[1].y;
            z1.y = tx * wf[1].y + ty * wf[1].x;
        }
        fwd_s(z0, xr8(z0.x), xr8(z0.y), 2);  fwd_s(z1, xr8(z1.x), xr8(z1.y), 2);
        fwd_s(z0, xr4(z0.x), xr4(z0.y), 3);  fwd_s(z1, xr4(z1.x), xr4(z1.y), 3);
        fwd_s(z0, qx2(z0.x), qx2(z0.y), 4);  fwd_s(z1, qx2(z1.x), qx2(z1.y), 4);
        {
            const float px = qx1(z0.x), py = qx1(z0.y);
            const float tx = fmaf(sg5, z0.x, px), ty = fmaf(sg5, z0.y, py);
            z0.x = tx * wtF0.x - ty * wtF0.y;
            z0.y = tx * wtF0.y + ty * wtF0.x;
        }
        {
            const float px = qx1(z1.x), py = qx1(z1.y);
            const float tx = fmaf(sg5, z1.x, px), ty = fmaf(sg5, z1.y, py);
            z1.x = tx * wtF1.x - ty * wtF1.y;
            z1.y = tx * wtF1.y + ty * wtF1.x;
        }
    };

    // inv stages 0..4 (shared mid-section, R17-verified)
    auto inv_mid = [&](float2& z0, float2& z1) {
        {
            const float px = qx1(z0.x), py = qx1(z0.y);
            const float nx = fmaf(Cai0_0.x, z0.x, fmaf(-Cai0_0.y, z0.y,
                             fmaf(Cbi0_0.x, px, -Cbi0_0.y * py)));
            const float ny = fmaf(Cai0_0.x, z0.y, fmaf(Cai0_0.y, z0.x,
                             fmaf(Cbi0_0.x, py, Cbi0_0.y * px)));
            z0 = make_float2(nx, ny);
        }
        {
            const float px = qx1(z1.x), py = qx1(z1.y);
            const float nx = fmaf(Cai0_1.x, z1.x, fmaf(-Cai0_1.y, z1.y,
                             fmaf(Cbi0_1.x, px, -Cbi0_1.y * py)));
            const float ny = fmaf(Cai0_1.x, z1.y, fmaf(Cai0_1.y, z1.x,
                             fmaf(Cbi0_1.x, py, Cbi0_1.y * px)));
            z1 = make_float2(nx, ny);
        }
        inv_sf(z0, qx2(z0.x), qx2(z0.y), 1);  inv_sf(z1, qx2(z1.x), qx2(z1.y), 1);
        inv_sf(z0, xr4(z0.x), xr4(z0.y), 2);  inv_sf(z1, xr4(z1.x), xr4(z1.y), 2);
        inv_sf(z0, xr8(z0.x), xr8(z0.y), 3);  inv_sf(z1, xr8(z1.x), xr8(z1.y), 3);
        {
            float lox, hix, loy, hiy;
            pswap16(z0.x, lox, hix); pswap16(z0.y, loy, hiy);
            z0.x = fmaf(wi[4].x, hix, fmaf(-wi[4].y, hiy, lox));
            z0.y = fmaf(wi[4].x, hiy, fmaf( wi[4].y, hix, loy));
            pswap16(z1.x, lox, hix); pswap16(z1.y, loy, hiy);
            z1.x = fmaf(wi[4].x, hix, fmaf(-wi[4].y, hiy, lox));
            z1.y = fmaf(wi[4].x, hiy, fmaf( wi[4].y, hix, loy));
        }
    };
    // Re-only tail: substep consumes only Re of (z0 +- cT128*z1)
    auto inv_re = [&](float2& z0, float2& z1, float& u0o, float& u1o) {
        inv_mid(z0, z1);
        float lox, hix, loy, hiy;
        pswap32(z0.x, lox, hix); pswap32(z0.y, loy, hiy);
        const float z0x = fmaf(wi[5].x, hix, fmaf(-wi[5].y, hiy, lox));
        pswap32(z1.x, lox, hix); pswap32(z1.y, loy, hiy);
        const float z1x = fmaf(wi[5].x, hix, fmaf(-wi[5].y, hiy, lox));
        const float z1y = fmaf(wi[5].x, hiy, fmaf( wi[5].y, hix, loy));
        const float re = z1x * cT128.x - z1y * cT128.y;
        u0o = z0x + re;
        u1o = z0x - re;
    };
    // Im-only tail: init (u = -Im) and snapshot (d = +Im)
    auto inv_im = [&](float2& z0, float2& z1, float& d0o, float& d1o) {
        inv_mid(z0, z1);
        float lox, hix, loy, hiy;
        pswap32(z0.x, lox, hix); pswap32(z0.y, loy, hiy);
        const float z0y = fmaf(wi[5].x, hiy, fmaf( wi[5].y, hix, loy));
        pswap32(z1.x, lox, hix); pswap32(z1.y, loy, hiy);
        const float z1x = fmaf(wi[5].x, hix, fmaf(-wi[5].y, hiy, lox));
        const float z1y = fmaf(wi[5].x, hiy, fmaf( wi[5].y, hix, loy));
        const float im = z1x * cT128.y + z1y * cT128.x;
        d0o = z0y + im;
        d1o = z0y - im;
    };

    // ---- substep g-sets (hot, named scalars; per spectral line kb0/kb1) ----
    DECL_G8(gS0); DECL_G8(gS1);
    {
        float mv[8];
        #pragma unroll
        for (int ka = 0; ka < 8; ++ka) {
            const int k = kb0 + 128 * ka;
            const float kk = (k <= 512) ? (float)k : (float)(k - 1024);
            const float kab = fabsf(kk);
            const float q = 1.0f - dtcR * (kab - nu * kab * kab);
            const float kkS = (k == 0 || k == 512) ? 0.0f : kk;
            mv[ka] = (1.0f - dt * kkS) / q;
        }
        BUILD_G8(gS0)
    }
    {
        float mv[8];
        #pragma unroll
        for (int ka = 0; ka < 8; ++ka) {
            const int k = kb1 + 128 * ka;
            const float kk = (k <= 512) ? (float)k : (float)(k - 1024);
            const float kab = fabsf(kk);
            const float q = 1.0f - dtcR * (kab - nu * kab * kab);
            const float kkS = (k == 0 || k == 512) ? 0.0f : kk;
            mv[ka] = (1.0f - dt * kkS) / q;
        }
        BUILD_G8(gS1)
    }

    int par = 0;
    float2 z0, z1;
    float u0, u1;
    const int n0 = 8 * l + w;        // point of reg0 (b=l)
    const int n1 = 512 + 8 * l + w;  // point of reg1 (b=64+l)

    // ---- init: d_to_u.  u = -Im(composite with m = kk) ----
    z0 = make_float2(x[b * NFFT + n0], 0.0f);
    z1 = make_float2(x[b * NFFT + n1], 0.0f);
    {
        DECL_G8(gD0); DECL_G8(gD1);
        {
            float mv[8];
            #pragma unroll
            for (int ka = 0; ka < 8; ++ka) {
                const int k = kb0 + 128 * ka;
                mv[ka] = (k <= 512) ? (float)k : (float)(k - 1024);
            }
            BUILD_G8(gD0)
        }
        {
            float mv[8];
            #pragma unroll
            for (int ka = 0; ka < 8; ++ka) {
                const int k = kb1 + 128 * ka;
                mv[ka] = (k <= 512) ? (float)k : (float)(k - 1024);
            }
            BUILD_G8(gD1)
        }
        fwd_all(z0, z1);
        EXCHANGE8(gD0, gD1);
        float d0, d1;
        inv_im(z0, z1, d0, d1);
        u0 = -d0;
        u1 = -d1;
    }

    for (int ot = 0; ot < nT; ++ot) {
        for (int ss = 0; ss < nsub; ++ss) {
            z0 = make_float2(u0, 0.5f * u0 * u0);
            z1 = make_float2(u1, 0.5f * u1 * u1);
            fwd_all(z0, z1);
            EXCHANGE8(gS0, gS1);   // fused: DFT8 + twiddles + S + invDFT8
            inv_re(z0, z1, u0, u1);
        }
        // snapshot: u_to_d. out = +Im(composite with m = 1/kk)
        {
            DECL_G8(gU0); DECL_G8(gU1);
            {
                float mv[8];
                #pragma unroll
                for (int ka = 0; ka < 8; ++ka) {
                    const int k = kb0 + 128 * ka;
                    const float kk = (k <= 512) ? (float)k : (float)(k - 1024);
                    mv[ka] = (k == 0) ? 0.0f : (1.0f / kk);
                }
                BUILD_G8(gU0)
            }
            {
                float mv[8];
                #pragma unroll
                for (int ka = 0; ka < 8; ++ka) {
                    const int k = kb1 + 128 * ka;
                    const float kk = (k <= 512) ? (float)k : (float)(k - 1024);
                    mv[ka] = (k == 0) ? 0.0f : (1.0f / kk);
                }
                BUILD_G8(gU1)
            }
            z0 = make_float2(u0, 0.0f);
            z1 = make_float2(u1, 0.0f);
            fwd_all(z0, z1);
            EXCHANGE8(gU0, gU1);
            float d0, d1;
            inv_im(z0, z1, d0, d1);
            out[(b * NFFT + n0) * nT + ot] = d0;
            out[(b * NFFT + n1) * nT + ot] = d1;
        }
    }
}

extern "C" void kernel_launch(void* const* d_in, const int* in_sizes, int n_in,
                              void* d_out, int out_size, void* d_ws, size_t ws_size,
                              hipStream_t stream) {
    const float* x     = (const float*)d_in[0];
    const float* nu_p  = (const float*)d_in[1];
    const float* dto_p = (const float*)d_in[2];
    const float* cr_p  = (const float*)d_in[3];
    const int*   nt_p  = (const int*)d_in[4];
    const int*   ns_p  = (const int*)d_in[5];
    float* out = (float*)d_out;

    const int B = in_sizes[0] / NFFT;  // C == 1
    siva_kernel<<<B, BLK, 0, stream>>>(x, nu_p, dto_p, cr_p, nt_p, ns_p, out);
}